// Round 1
// baseline (40.280 us; speedup 1.0000x reference)
//
#include <hip/hip_runtime.h>

#define NB 8          // batches
#define NP 4096       // points per cloud (N == M)
#define MC 1024       // targets per LDS chunk
#define THREADS 256
#define PPT 2         // query points per thread
#define MSPLIT (NP / MC)
#define SCALE (1.0f / 32768.0f)   // 1/(B*N), same for both directions

__device__ __forceinline__ float blockReduceSum(float v) {
  #pragma unroll
  for (int off = 32; off > 0; off >>= 1)
    v += __shfl_down(v, off, 64);
  __shared__ float smem[THREADS / 64];
  int lane = threadIdx.x & 63;
  int wid  = threadIdx.x >> 6;
  if (lane == 0) smem[wid] = v;
  __syncthreads();
  float r = 0.f;
  if (threadIdx.x == 0) {
    #pragma unroll
    for (int w = 0; w < THREADS / 64; ++w) r += smem[w];
  }
  return r;
}

__global__ void chamfer_init_kernel(unsigned int* wsmin, float* out, int nws) {
  int i = blockIdx.x * blockDim.x + threadIdx.x;
  if (i == 0) out[0] = 0.0f;
  if (wsmin != nullptr) {
    for (int k = i; k < nws; k += gridDim.x * blockDim.x)
      wsmin[k] = 0x7f800000u;   // +inf bit pattern
  }
}

// For each query point p: min_j (|p|^2 + |t_j|^2 - 2 p.t_j)
//   = |p|^2 + 2 * min_j e_j,  e_j = |t_j|^2/2 - p.t_j   (3 FMAs per pair)
template <bool USE_WS>
__global__ __launch_bounds__(THREADS, 2)
void chamfer_min_kernel(const float* __restrict__ pred,
                        const float* __restrict__ tgt,
                        unsigned int* __restrict__ wsmin,
                        float* __restrict__ out) {
  int bid = blockIdx.x;
  int mc0, msteps, pc, b, dir;
  if (USE_WS) {               // 512 blocks: [dir(2)][b(8)][pc(8)][mc(4)]
    mc0 = bid & 3; msteps = 1;
    pc = (bid >> 2) & 7; b = (bid >> 5) & 7; dir = bid >> 8;
  } else {                    // 128 blocks: [dir(2)][b(8)][pc(8)]
    mc0 = 0; msteps = MSPLIT;
    pc = bid & 7; b = (bid >> 3) & 7; dir = bid >> 6;
  }

  const float* psrc = (dir == 0 ? pred : tgt) + (size_t)b * NP * 3;
  const float* tsrc = (dir == 0 ? tgt : pred) + (size_t)b * NP * 3;

  float px[PPT], py[PPT], pz[PPT], pp[PPT], bestA[PPT], bestB[PPT];
  int n[PPT];
  #pragma unroll
  for (int p = 0; p < PPT; ++p) {
    n[p] = pc * (THREADS * PPT) + p * THREADS + (int)threadIdx.x;
    px[p] = psrc[3 * n[p] + 0];
    py[p] = psrc[3 * n[p] + 1];
    pz[p] = psrc[3 * n[p] + 2];
    pp[p] = px[p] * px[p] + py[p] * py[p] + pz[p] * pz[p];
    bestA[p] = 1e30f; bestB[p] = 1e30f;
  }

  __shared__ float4 sh[MC];

  for (int step = 0; step < msteps; ++step) {
    int mbase = (mc0 + step) * MC;
    for (int t = (int)threadIdx.x; t < MC; t += THREADS) {
      const float* q = tsrc + 3 * (size_t)(mbase + t);
      float x = q[0], y = q[1], z = q[2];
      sh[t] = make_float4(x, y, z, 0.5f * (x * x + y * y + z * z));
    }
    __syncthreads();

    #pragma unroll 2
    for (int j = 0; j < MC; j += 4) {
      float4 t0 = sh[j + 0];
      float4 t1 = sh[j + 1];
      float4 t2 = sh[j + 2];
      float4 t3 = sh[j + 3];
      #pragma unroll
      for (int p = 0; p < PPT; ++p) {
        float e0 = __builtin_fmaf(-px[p], t0.x,
                   __builtin_fmaf(-py[p], t0.y,
                   __builtin_fmaf(-pz[p], t0.z, t0.w)));
        float e1 = __builtin_fmaf(-px[p], t1.x,
                   __builtin_fmaf(-py[p], t1.y,
                   __builtin_fmaf(-pz[p], t1.z, t1.w)));
        float e2 = __builtin_fmaf(-px[p], t2.x,
                   __builtin_fmaf(-py[p], t2.y,
                   __builtin_fmaf(-pz[p], t2.z, t2.w)));
        float e3 = __builtin_fmaf(-px[p], t3.x,
                   __builtin_fmaf(-py[p], t3.y,
                   __builtin_fmaf(-pz[p], t3.z, t3.w)));
        bestA[p] = fminf(bestA[p], fminf(e0, e1));
        bestB[p] = fminf(bestB[p], fminf(e2, e3));
      }
    }
    __syncthreads();
  }

  float local = 0.f;
  #pragma unroll
  for (int p = 0; p < PPT; ++p) {
    float d = pp[p] + 2.0f * fminf(bestA[p], bestB[p]);
    d = fmaxf(d, 0.0f);   // squared distance; clamp fp-rounding negatives so
                          // uint-ordered atomicMin is a valid float min
    if (USE_WS) {
      atomicMin(&wsmin[((size_t)dir * NB + b) * NP + n[p]], __float_as_uint(d));
    } else {
      local += d;
    }
  }
  if (!USE_WS) {
    float s = blockReduceSum(local);
    if (threadIdx.x == 0) atomicAdd(out, s * SCALE);
  }
}

__global__ void chamfer_reduce_kernel(const unsigned int* __restrict__ wsmin,
                                      float* __restrict__ out) {
  int i = blockIdx.x * blockDim.x + threadIdx.x;   // exactly 2*NB*NP threads
  float v = __uint_as_float(wsmin[i]);
  float s = blockReduceSum(v);
  if (threadIdx.x == 0) atomicAdd(out, s * SCALE);
}

extern "C" void kernel_launch(void* const* d_in, const int* in_sizes, int n_in,
                              void* d_out, int out_size, void* d_ws, size_t ws_size,
                              hipStream_t stream) {
  const float* pred = (const float*)d_in[0];
  const float* tgt  = (const float*)d_in[1];
  float* out = (float*)d_out;

  const int nws = 2 * NB * NP;                       // 65536 per-point mins
  const size_t ws_needed = (size_t)nws * sizeof(unsigned int);

  if (ws_size >= ws_needed && d_ws != nullptr) {
    unsigned int* wsmin = (unsigned int*)d_ws;
    chamfer_init_kernel<<<256, THREADS, 0, stream>>>(wsmin, out, nws);
    chamfer_min_kernel<true><<<512, THREADS, 0, stream>>>(pred, tgt, wsmin, out);
    chamfer_reduce_kernel<<<nws / THREADS, THREADS, 0, stream>>>(wsmin, out);
  } else {
    chamfer_init_kernel<<<1, THREADS, 0, stream>>>(nullptr, out, 0);
    chamfer_min_kernel<false><<<128, THREADS, 0, stream>>>(pred, tgt, nullptr, out);
  }
}

// Round 2
// 34.790 us; speedup vs baseline: 1.1578x; 1.1578x over previous
//
#include <hip/hip_runtime.h>

#define NB 8                      // batches
#define NP 4096                   // points per cloud (N == M)
#define MC 256                    // targets per LDS chunk
#define THREADS 256
#define PPT 8                     // query points per thread
#define NSLOT (NP / MC)           // 16 target chunks
#define NPTS (2 * NB * NP)        // 65536 per-point mins (both directions)
#define SCALE (1.0f / 32768.0f)   // 1/(B*N), same for both directions

__device__ __forceinline__ float blockReduceSum(float v) {
  #pragma unroll
  for (int off = 32; off > 0; off >>= 1)
    v += __shfl_down(v, off, 64);
  __shared__ float smem[THREADS / 64];
  int lane = threadIdx.x & 63;
  int wid  = threadIdx.x >> 6;
  if (lane == 0) smem[wid] = v;
  __syncthreads();
  float r = 0.f;
  if (threadIdx.x == 0) {
    #pragma unroll
    for (int w = 0; w < THREADS / 64; ++w) r += smem[w];
  }
  return r;
}

__global__ void chamfer_zero_kernel(float* out) {
  if (threadIdx.x == 0) out[0] = 0.0f;
}

// For each query point p: min_j (|p|^2 + |t_j|^2 - 2 p.t_j)
//   = |p|^2 + 2 * min_j e_j,  e_j = |t_j|^2/2 - p.t_j   (3 FMAs per pair)
// USE_WS: 512 blocks, each handles one (dir,b,pc,mc) cell; writes its
// per-chunk partial d to a private ws slot (no atomics, fully deterministic).
template <bool USE_WS>
__global__ __launch_bounds__(THREADS, 2)
void chamfer_min_kernel(const float* __restrict__ pred,
                        const float* __restrict__ tgt,
                        float* __restrict__ wspart,
                        float* __restrict__ out) {
  const int tid = (int)threadIdx.x;
  const int bid = (int)blockIdx.x;
  int mc0, msteps, pc, b, dir;
  if (USE_WS) {              // 512 blocks: [dir(2)][b(8)][pc(2)][mc(16)]
    mc0 = bid & 15; msteps = 1;
    pc = (bid >> 4) & 1; b = (bid >> 5) & 7; dir = (bid >> 8) & 1;
    if (bid == 0 && tid == 0) out[0] = 0.0f;   // stream-ordered before reduce
  } else {                   // 32 blocks: [dir(2)][b(8)][pc(2)]
    mc0 = 0; msteps = NSLOT;
    pc = bid & 1; b = (bid >> 1) & 7; dir = (bid >> 4) & 1;
  }

  const float* psrc = (dir == 0 ? pred : tgt) + (size_t)b * NP * 3;
  const float* tsrc = (dir == 0 ? tgt : pred) + (size_t)b * NP * 3;

  float px[PPT], py[PPT], pz[PPT], pp[PPT], bA[PPT], bB[PPT];
  int n[PPT];
  #pragma unroll
  for (int p = 0; p < PPT; ++p) {
    n[p] = pc * (THREADS * PPT) + p * THREADS + tid;
    px[p] = psrc[3 * n[p] + 0];
    py[p] = psrc[3 * n[p] + 1];
    pz[p] = psrc[3 * n[p] + 2];
    pp[p] = px[p] * px[p] + py[p] * py[p] + pz[p] * pz[p];
    bA[p] = 1e30f; bB[p] = 1e30f;
  }

  __shared__ float4 sh[MC];

  for (int step = 0; step < msteps; ++step) {
    int mbase = (mc0 + step) * MC;
    for (int t = tid; t < MC; t += THREADS) {
      const float* q = tsrc + 3 * (size_t)(mbase + t);
      float x = q[0], y = q[1], z = q[2];
      sh[t] = make_float4(x, y, z, 0.5f * (x * x + y * y + z * z));
    }
    __syncthreads();

    for (int j = 0; j < MC; j += 4) {
      float4 t0 = sh[j + 0];
      float4 t1 = sh[j + 1];
      float4 t2 = sh[j + 2];
      float4 t3 = sh[j + 3];
      #pragma unroll
      for (int p = 0; p < PPT; ++p) {
        float e0 = __builtin_fmaf(-px[p], t0.x,
                   __builtin_fmaf(-py[p], t0.y,
                   __builtin_fmaf(-pz[p], t0.z, t0.w)));
        float e1 = __builtin_fmaf(-px[p], t1.x,
                   __builtin_fmaf(-py[p], t1.y,
                   __builtin_fmaf(-pz[p], t1.z, t1.w)));
        float e2 = __builtin_fmaf(-px[p], t2.x,
                   __builtin_fmaf(-py[p], t2.y,
                   __builtin_fmaf(-pz[p], t2.z, t2.w)));
        float e3 = __builtin_fmaf(-px[p], t3.x,
                   __builtin_fmaf(-py[p], t3.y,
                   __builtin_fmaf(-pz[p], t3.z, t3.w)));
        bA[p] = fminf(fminf(bA[p], e0), e1);   // v_min3 candidate
        bB[p] = fminf(fminf(bB[p], e2), e3);
      }
    }
    __syncthreads();
  }

  if (USE_WS) {
    float* dst = wspart + (size_t)mc0 * NPTS + ((size_t)dir * NB + b) * NP;
    #pragma unroll
    for (int p = 0; p < PPT; ++p) {
      dst[n[p]] = pp[p] + 2.0f * fminf(bA[p], bB[p]);
    }
  } else {
    float local = 0.f;
    #pragma unroll
    for (int p = 0; p < PPT; ++p) {
      float d = pp[p] + 2.0f * fminf(bA[p], bB[p]);
      local += fmaxf(d, 0.0f);
    }
    float s = blockReduceSum(local);
    if (tid == 0) atomicAdd(out, s * SCALE);
  }
}

// One thread per point: min over the 16 chunk-partials, then sum-reduce.
__global__ __launch_bounds__(THREADS)
void chamfer_reduce_kernel(const float* __restrict__ wspart,
                           float* __restrict__ out) {
  int i = (int)blockIdx.x * THREADS + (int)threadIdx.x;   // 0..NPTS-1
  float best = wspart[i];
  #pragma unroll
  for (int s = 1; s < NSLOT; ++s)
    best = fminf(best, wspart[(size_t)s * NPTS + i]);
  float d = fmaxf(best, 0.0f);
  float ssum = blockReduceSum(d);
  if (threadIdx.x == 0) atomicAdd(out, ssum * SCALE);
}

extern "C" void kernel_launch(void* const* d_in, const int* in_sizes, int n_in,
                              void* d_out, int out_size, void* d_ws, size_t ws_size,
                              hipStream_t stream) {
  const float* pred = (const float*)d_in[0];
  const float* tgt  = (const float*)d_in[1];
  float* out = (float*)d_out;

  const size_t ws_needed = (size_t)NSLOT * NPTS * sizeof(float);   // 4 MB

  if (ws_size >= ws_needed && d_ws != nullptr) {
    float* wspart = (float*)d_ws;
    chamfer_min_kernel<true><<<512, THREADS, 0, stream>>>(pred, tgt, wspart, out);
    chamfer_reduce_kernel<<<NPTS / THREADS, THREADS, 0, stream>>>(wspart, out);
  } else {
    chamfer_zero_kernel<<<1, 64, 0, stream>>>(out);
    chamfer_min_kernel<false><<<32, THREADS, 0, stream>>>(pred, tgt, nullptr, out);
  }
}